// Round 21
// baseline (116.775 us; speedup 1.0000x reference)
//
#include <hip/hip_runtime.h>
#include <math.h>

// Problem dims
constexpr int B_ = 4, N_ = 256, D_ = 256, H_ = 8, E_ = 32, FF_ = 512, DK_ = 32;
constexpr float SCALE_ = 0.17677669529663687f;  // DK^-0.5
constexpr float NEG_ = -9.0e15f;

typedef unsigned short u16;
typedef unsigned int u32;
typedef __attribute__((ext_vector_type(8))) short bf16x8;
typedef __attribute__((ext_vector_type(4))) float f32x4;
typedef __attribute__((ext_vector_type(8))) _Float16 f16x8;
typedef __attribute__((ext_vector_type(2))) _Float16 f16x2;
typedef __attribute__((ext_vector_type(2))) __fp16 fp16x2_raw;

__device__ __forceinline__ float gelu_fast(float x) {
  float u = x * x;
  float q = x * fmaf(-0.071354816272f, u, -1.5957691216057308f);
  float e = __expf(q);
  return x * __builtin_amdgcn_rcpf(1.f + e);
}

__device__ __forceinline__ f16x2 cvt_pk_f16(float a, float b) {
  union { fp16x2_raw i; f16x2 o; } u;
  u.i = __builtin_amdgcn_cvt_pkrtz(a, b);
  return u.o;
}

// Packed-f16 gelu pair (e-FFN hot loop). |h| <= 0.85 hard bound.
__device__ __forceinline__ f16x2 gelu_pk(f16x2 x) {
  const f16x2 C5 = {(_Float16)0.0199471f, (_Float16)0.0199471f};
  const f16x2 C3 = {(_Float16)-0.1329807f, (_Float16)-0.1329807f};
  const f16x2 C1 = {(_Float16)0.7978846f, (_Float16)0.7978846f};
  const f16x2 HALF = {(_Float16)0.5f, (_Float16)0.5f};
  const f16x2 ONE = {(_Float16)1.f, (_Float16)1.f};
  f16x2 w = x * x;
  f16x2 p = w * C5 + C3;
  p = w * p + C1;
  f16x2 t = x * p + ONE;
  f16x2 hx = x * HALF;
  return hx * t;
}

__device__ __forceinline__ u16 f2bf(float x) {
  union { float f; u32 u; } v; v.f = x;
  u32 r = v.u + 0x7fffu + ((v.u >> 16) & 1u);
  return (u16)(r >> 16);
}

__device__ __forceinline__ u32 pk2bf(float a, float b) {
  union { float f; u32 u; } x, y; x.f = a; y.f = b;
  u32 ra = (x.u + 0x7fffu + ((x.u >> 16) & 1u)) >> 16;
  u32 rb = (y.u + 0x7fffu + ((y.u >> 16) & 1u)) & 0xffff0000u;
  return ra | rb;
}

__device__ __forceinline__ float bf2f(u16 h) {
  union { u32 u; float f; } v; v.u = ((u32)h) << 16; return v.f;
}

// ============ merged FRONT kernel: pack (0..319) | gnorm_part(x) (320..447)
// ============ | ln_e_fused (448..1471). All three mutually independent.
__global__ __launch_bounds__(256) void front_kernel(
    const float* __restrict__ Wq, const float* __restrict__ Wk,
    const float* __restrict__ Wv, const float* __restrict__ Wo,
    const float* __restrict__ W1, const float* __restrict__ W2,
    const float* __restrict__ W1e, const float* __restrict__ W2e,
    const float* __restrict__ Woe, const float* __restrict__ Wap,
    const float* __restrict__ bap,
    u16* __restrict__ wxp, u16* __restrict__ w1p, u16* __restrict__ w2p,
    u16* __restrict__ woep, u16* __restrict__ wwp,
    const float* __restrict__ x, float2* __restrict__ part,
    const float* __restrict__ e_in, const float* __restrict__ lnw,
    const float* __restrict__ lnb, const float* __restrict__ Wep,
    const float* __restrict__ bep, const int* __restrict__ adj1,
    u16* __restrict__ e_nb, u16* __restrict__ eb16) {
  int bx = blockIdx.x;
  int tid = threadIdx.x;
  if (bx < 256) {
    int idx = bx * 256 + tid;
    const float* W;
    int rel, Nn, kcs, cmask;
    if (idx < 32768) {
      int m = idx >> 13;
      W = (m == 0) ? Wq : (m == 1) ? Wk : (m == 2) ? Wv : Wo;
      rel = idx & 8191; Nn = 256; kcs = 4; cmask = 15;
    } else if (idx < 49152) {
      W = W1; rel = idx - 32768; Nn = 512; kcs = 5; cmask = 31;
    } else {
      W = W2; rel = idx - 49152; Nn = 256; kcs = 4; cmask = 15;
    }
    int fr = rel >> 6, lane = rel & 63;
    int kc = fr >> kcs, ctt = fr & cmask;
    int krow = kc * 32 + ((lane >> 4) << 3);
    int col = ctt * 16 + (lane & 15);
    u16 out[8];
#pragma unroll
    for (int j = 0; j < 8; j++)
      out[j] = f2bf(W[(size_t)(krow + j) * Nn + col]);
    uint4* dst = (uint4*)(wxp + ((size_t)idx << 3));
    *dst = make_uint4(((u32)out[0]) | ((u32)out[1] << 16),
                      ((u32)out[2]) | ((u32)out[3] << 16),
                      ((u32)out[4]) | ((u32)out[5] << 16),
                      ((u32)out[6]) | ((u32)out[7] << 16));
  } else if (bx < 320) {
    int idx = (bx - 256) * 256 + tid;  // 0..16383
    {
      int t = idx >> 9, rem = idx & 511, lane = rem >> 3, j = rem & 7;
      int k = ((lane >> 4) << 3) + j, col = (t << 4) + (lane & 15);
      w1p[idx] = f2bf(W1e[k * FF_ + col]);
    }
    {
      int f = idx >> 9, rem = idx & 511, lane = rem >> 3, j = rem & 7;
      int nc = f >> 2, kp = (f >> 1) & 1, ct = f & 1;
      int unit = nc * 64 + kp * 32 + 16 * (j >> 2) + 4 * (lane >> 4) + (j & 3);
      int col = ct * 16 + (lane & 15);
      union { _Float16 h; u16 u; } cv;
      cv.h = (_Float16)W2e[unit * E_ + col];
      w2p[idx] = cv.u;
    }
    if (idx < 1024) {
      int ct = idx >> 9, rem = idx & 511, lane = rem >> 3, j = rem & 7;
      int k = ((lane >> 4) << 3) + j, col = ct * 16 + (lane & 15);
      woep[idx] = f2bf(Woe[k * E_ + col]);
      float v = 0.f;
      if (k < 8) {
        for (int e = 0; e < 32; e++) v += Wap[k * E_ + e] * Woe[e * E_ + col];
      } else if (k == 8) {
        for (int e = 0; e < 32; e++) v += bap[e] * Woe[e * E_ + col];
      }
      wwp[idx] = f2bf(v);
    }
  } else if (bx < 448) {
    int i = bx - 320;
    int b = i & 3, by = (i >> 2) & 3, nz = i >> 4;
    int d = tid & 63, gn = tid >> 6;
    __shared__ float2 red[4][64];
    const float* xp = x + ((size_t)b * N_ * D_) + (size_t)(nz * 32 + gn * 8) * D_ + by * 64 + d;
    float s = 0.f, s2 = 0.f;
#pragma unroll
    for (int i2 = 0; i2 < 8; i2++) { float v = xp[(size_t)i2 * D_]; s += v; s2 += v * v; }
    red[gn][d] = make_float2(s, s2);
    __syncthreads();
    if (tid < 64) {
      float2 a = red[0][d], b2 = red[1][d], c = red[2][d], e = red[3][d];
      part[((b * 4 + by) * 8 + nz) * 64 + d] =
          make_float2(a.x + b2.x + c.x + e.x, a.y + b2.y + c.y + e.y);
    }
  } else {
    size_t t = (size_t)(bx - 448) * 256 + tid;
    int b = (int)(t >> 16), n2 = (int)((t >> 8) & 255), n1 = (int)(t & 255);
    size_t rowid = ((size_t)(b * N_ + n1)) * N_ + n2;
    const float4* ip = (const float4*)(e_in + rowid * E_);
    float4 v[8];
    float s = 0.f;
#pragma unroll
    for (int i = 0; i < 8; i++) { v[i] = ip[i]; s += v[i].x + v[i].y + v[i].z + v[i].w; }
    float mu = s * (1.f / E_);
    float q = 0.f;
#pragma unroll
    for (int i = 0; i < 8; i++) {
      float a = v[i].x - mu, b2 = v[i].y - mu, c = v[i].z - mu, dd = v[i].w - mu;
      q += a * a + b2 * b2 + c * c + dd * dd;
    }
    float inv = rsqrtf(q * (1.f / E_) + 1e-5f);
    float ov[32];
#pragma unroll
    for (int i = 0; i < 8; i++) {
      float4 wv = ((const float4*)lnw)[i];
      float4 bv = ((const float4*)lnb)[i];
      ov[4 * i + 0] = wv.x * (v[i].x - mu) * inv + bv.x;
      ov[4 * i + 1] = wv.y * (v[i].y - mu) * inv + bv.y;
      ov[4 * i + 2] = wv.z * (v[i].z - mu) * inv + bv.z;
      ov[4 * i + 3] = wv.w * (v[i].w - mu) * inv + bv.w;
    }
    u32 pk[16];
#pragma unroll
    for (int i = 0; i < 16; i++) pk[i] = pk2bf(ov[2 * i], ov[2 * i + 1]);
    uint4* op = (uint4*)(e_nb + rowid * E_);
    op[0] = make_uint4(pk[0], pk[1], pk[2], pk[3]);
    op[1] = make_uint4(pk[4], pk[5], pk[6], pk[7]);
    op[2] = make_uint4(pk[8], pk[9], pk[10], pk[11]);
    op[3] = make_uint4(pk[12], pk[13], pk[14], pk[15]);
    float acc[8];
#pragma unroll
    for (int h = 0; h < 8; h++) acc[h] = bep[h];
#pragma unroll
    for (int e = 0; e < 32; e++) {
      float re = ov[e];
#pragma unroll
      for (int h = 0; h < 8; h++) acc[h] = fmaf(re, Wep[e * 8 + h], acc[h]);
    }
    float a1f = (float)adj1[t];
#pragma unroll
    for (int h = 0; h < 8; h++)
      eb16[(((size_t)b * H_ + h) * N_ + n2) * N_ + n1] = f2bf(acc[h] * a1f);
  }
}

// ------------------------------------------- gnorm stage kernels
__global__ __launch_bounds__(256) void gnorm_part_kernel(
    const float* __restrict__ x, float2* __restrict__ part) {
  int b = blockIdx.x, by = blockIdx.y, nz = blockIdx.z;
  int tid = threadIdx.x, d = tid & 63, gn = tid >> 6;
  __shared__ float2 red[4][64];
  const float* xp = x + ((size_t)b * N_ * D_) + (size_t)(nz * 32 + gn * 8) * D_ + by * 64 + d;
  float s = 0.f, s2 = 0.f;
#pragma unroll
  for (int i = 0; i < 8; i++) { float v = xp[(size_t)i * D_]; s += v; s2 += v * v; }
  red[gn][d] = make_float2(s, s2);
  __syncthreads();
  if (tid < 64) {
    float2 a = red[0][d], b2 = red[1][d], c = red[2][d], e = red[3][d];
    part[((b * 4 + by) * 8 + nz) * 64 + d] =
        make_float2(a.x + b2.x + c.x + e.x, a.y + b2.y + c.y + e.y);
  }
}

__global__ __launch_bounds__(256) void gnorm_apply_kernel(
    const float* __restrict__ x, const float* __restrict__ w,
    const float* __restrict__ bw, const float* __restrict__ ms,
    const float2* __restrict__ part, float* __restrict__ out) {
  int b = blockIdx.x, by = blockIdx.y, nz = blockIdx.z;
  int tid = threadIdx.x, d = tid & 63, gn = tid >> 6;
  int d0 = by * 64;
  float s = 0.f, s2 = 0.f;
#pragma unroll
  for (int i = 0; i < 8; i++) {
    float2 p = part[((b * 4 + by) * 8 + i) * 64 + d];
    s += p.x; s2 += p.y;
  }
  float mean = s * (1.f / N_);
  float m2 = ms[d0 + d] * mean;
  float var = fmaxf(s2 * (1.f / N_) - 2.f * m2 * mean + m2 * m2, 0.f);
  float inv = 1.f / (sqrtf(var) + 1e-6f);
  float W = w[d0 + d], Bb = bw[d0 + d];
  const float* xp = x + ((size_t)b * N_ * D_) + (size_t)(nz * 32 + gn * 8) * D_ + d0 + d;
  float* op = out + ((size_t)b * N_ * D_) + (size_t)(nz * 32 + gn * 8) * D_ + d0 + d;
#pragma unroll
  for (int i = 0; i < 8; i++)
    op[(size_t)i * D_] = W * (xp[(size_t)i * D_] - m2) * inv + Bb;
}

// --------------- bf16 MFMA GEMM: C = maybe_gelu((A@W + bias)*scale) [+ res]
template <int GELU>
__global__ __launch_bounds__(256) void mgemm_kernel(
    const float* __restrict__ A, const u16* __restrict__ Wp,
    const float* __restrict__ bias, const float* __restrict__ res,
    float* __restrict__ C, int K, int Nn, float scale) {
  int tid = threadIdx.x;
  int w = tid >> 6, l = tid & 63;
  int rt = w & 1, cts = (w >> 1) << 1;
  int row0 = blockIdx.y * 32, col0 = blockIdx.x * 64;
  int nf = Nn >> 4;
  f32x4 acc[2];
#pragma unroll
  for (int c2 = 0; c2 < 2; c2++) {
    float bb = bias[col0 + (cts + c2) * 16 + (l & 15)];
    acc[c2] = (f32x4){bb, bb, bb, bb};
  }
  int arow = row0 + rt * 16 + (l & 15);
  const float* ap = A + (size_t)arow * K + ((l >> 4) << 3);
  int nkc = K >> 5;
  for (int kc = 0; kc < nkc; kc++) {
    float4 a0 = *(const float4*)(ap + kc * 32);
    float4 a1 = *(const float4*)(ap + kc * 32 + 4);
    union { bf16x8 v; u32 u[4]; } af;
    af.u[0] = pk2bf(a0.x, a0.y); af.u[1] = pk2bf(a0.z, a0.w);
    af.u[2] = pk2bf(a1.x, a1.y); af.u[3] = pk2bf(a1.z, a1.w);
#pragma unroll
    for (int c2 = 0; c2 < 2; c2++) {
      bf16x8 wf = *(const bf16x8*)(Wp + (((size_t)kc * nf + (col0 >> 4) + cts + c2) << 9) + (l << 3));
      acc[c2] = __builtin_amdgcn_mfma_f32_16x16x32_bf16(af.v, wf, acc[c2], 0, 0, 0);
    }
  }
#pragma unroll
  for (int c2 = 0; c2 < 2; c2++) {
    int col = col0 + (cts + c2) * 16 + (l & 15);
#pragma unroll
    for (int rr = 0; rr < 4; rr++) {
      int row = row0 + rt * 16 + (l >> 4) * 4 + rr;
      float v = acc[c2][rr] * scale;
      if (GELU) v = gelu_fast(v);
      if (res) v += res[(size_t)row * Nn + col];
      C[(size_t)row * Nn + col] = v;
    }
  }
}

// --------------- fused QKV via MFMA (z picks target), K=N=256
__global__ __launch_bounds__(256) void qkv_mfma_kernel(
    const float* __restrict__ A, const u16* __restrict__ wxp,
    const float* __restrict__ bq, const float* __restrict__ bk,
    const float* __restrict__ bv,
    float* __restrict__ q, float* __restrict__ k, float* __restrict__ v) {
  int z = blockIdx.z;
  const u16* Wp = wxp + (size_t)z * 65536;
  const float* bias = (z == 0) ? bq : (z == 1) ? bk : bv;
  float* C = (z == 0) ? q : (z == 1) ? k : v;
  float scale = (z == 0) ? SCALE_ : 1.f;
  int tid = threadIdx.x;
  int w = tid >> 6, l = tid & 63;
  int rt = w & 1, cts = (w >> 1) << 1;
  int row0 = blockIdx.y * 32, col0 = blockIdx.x * 64;
  f32x4 acc[2];
#pragma unroll
  for (int c2 = 0; c2 < 2; c2++) {
    float bb = bias[col0 + (cts + c2) * 16 + (l & 15)];
    acc[c2] = (f32x4){bb, bb, bb, bb};
  }
  int arow = row0 + rt * 16 + (l & 15);
  const float* ap = A + (size_t)arow * D_ + ((l >> 4) << 3);
#pragma unroll
  for (int kc = 0; kc < 8; kc++) {
    float4 a0 = *(const float4*)(ap + kc * 32);
    float4 a1 = *(const float4*)(ap + kc * 32 + 4);
    union { bf16x8 v; u32 u[4]; } af;
    af.u[0] = pk2bf(a0.x, a0.y); af.u[1] = pk2bf(a0.z, a0.w);
    af.u[2] = pk2bf(a1.x, a1.y); af.u[3] = pk2bf(a1.z, a1.w);
#pragma unroll
    for (int c2 = 0; c2 < 2; c2++) {
      bf16x8 wf = *(const bf16x8*)(Wp + (((size_t)kc * 16 + (col0 >> 4) + cts + c2) << 9) + (l << 3));
      acc[c2] = __builtin_amdgcn_mfma_f32_16x16x32_bf16(af.v, wf, acc[c2], 0, 0, 0);
    }
  }
#pragma unroll
  for (int c2 = 0; c2 < 2; c2++) {
    int col = col0 + (cts + c2) * 16 + (l & 15);
#pragma unroll
    for (int rr = 0; rr < 4; rr++) {
      int row = row0 + rt * 16 + (l >> 4) * 4 + rr;
      C[(size_t)row * D_ + col] = acc[c2][rr] * scale;
    }
  }
}

// ===== FUSED scores + dual-softmax + PV, v3: 8 q-rows/block, grid (32,8,4).
// K row direct to regs; V staged transposed; 3 blocks/CU resident.
__global__ __launch_bounds__(256) void scores_attn_kernel(
    const float* __restrict__ q, const float* __restrict__ k,
    const float* __restrict__ v, const int* __restrict__ adj,
    const int* __restrict__ use_adj, const float* __restrict__ ab,
    const u16* __restrict__ eb16,
    u16* __restrict__ scoresT, float* __restrict__ out) {
  int it2 = blockIdx.x, h = blockIdx.y, b = blockIdx.z;  // it2: 0..31, 8 rows
  int tid = threadIdx.x;
  __shared__ float qt[8][33];
  __shared__ u16 sc[8][260];      // bf16 scores
  __shared__ float vst[32][260];  // V transposed [d][j]
  __shared__ float psw[4][256];   // wave-private p rows

  // ---- K row for this lane: direct global -> regs (32 contiguous floats)
  float kreg[32];
  {
    const float4* kp = (const float4*)(k + ((size_t)b * N_ + tid) * D_ + h * DK_);
#pragma unroll
    for (int i = 0; i < 8; i++) {
      float4 kv = kp[i];
      kreg[4 * i] = kv.x; kreg[4 * i + 1] = kv.y;
      kreg[4 * i + 2] = kv.z; kreg[4 * i + 3] = kv.w;
    }
  }
  // ---- stage Q (8 rows, 1 elem/thread) and V (transposed)
  qt[tid >> 5][tid & 31] = q[((size_t)b * N_ + it2 * 8 + (tid >> 5)) * D_ + h * DK_ + (tid & 31)];
  for (int i2 = 0; i2 < 32; i2++) {
    int f = tid + (i2 << 8);
    int j = f >> 5, d = f & 31;
    vst[d][j] = v[((size_t)b * N_ + j) * D_ + h * DK_ + d];
  }
  __syncthreads();

  // ---- phase A: scores for 8 rows -> sc (LDS) + scoresT (global)
  int ua = use_adj[0];
  u32 sbuf[4];
  float sprev = 0.f;
#pragma unroll
  for (int r = 0; r < 8; r++) {
    float s = 0.f;
#pragma unroll
    for (int d = 0; d < 32; d++) s = fmaf(qt[r][d], kreg[d], s);
    int i = it2 * 8 + r;
    if (ua) {
      int a = adj[((size_t)b * N_ + i) * N_ + tid];
      s = (a > 0 ? s : NEG_) * (float)a;
    }
    sc[r][tid] = f2bf(s);
    if (r & 1) sbuf[r >> 1] = pk2bf(sprev, s); else sprev = s;
  }
  *(uint4*)(scoresT + ((((size_t)(b * N_ + tid)) * 8 + h) << 8) + (it2 << 3)) =
      make_uint4(sbuf[0], sbuf[1], sbuf[2], sbuf[3]);
  __syncthreads();   // sc visible

  // ---- phase B: softmax + PV; 4 waves x 2 rows
  int w = tid >> 6, l = tid & 63;
  int d = l & 31, hf = l >> 5;
  for (int rr = 0; rr < 2; rr++) {
    int lr = w * 2 + rr;          // local row 0..7
    int i = it2 * 8 + lr;
    size_t base = (((size_t)b * H_ + h) * N_ + i) * N_ + l * 4;
    uint2 sB = *(const uint2*)&sc[lr][l * 4];
    float s4x = bf2f((u16)(sB.x & 0xffff)), s4y = bf2f((u16)(sB.x >> 16));
    float s4z = bf2f((u16)(sB.y & 0xffff)), s4w = bf2f((u16)(sB.y >> 16));
    uint2 eB = *(const uint2*)(eb16 + base);
    float e4x = bf2f((u16)(eB.x & 0xffff)), e4y = bf2f((u16)(eB.x >> 16));
    float e4z = bf2f((u16)(eB.y & 0xffff)), e4w = bf2f((u16)(eB.y >> 16));
    float4 a4 = *(const float4*)(ab + base);
    float sl[4] = {s4x * a4.x, s4y * a4.y, s4z * a4.z, s4w * a4.w};
    float scv[4] = {s4x * e4x, s4y * e4y, s4z * e4z, s4w * e4w};
    float ml = fmaxf(fmaxf(sl[0], sl[1]), fmaxf(sl[2], sl[3]));
    float mc = fmaxf(fmaxf(scv[0], scv[1]), fmaxf(scv[2], scv[3]));
#pragma unroll
    for (int o = 32; o; o >>= 1) { ml = fmaxf(ml, __shfl_xor(ml, o)); mc = fmaxf(mc, __shfl_xor(mc, o)); }
    float el[4], ec[4];
#pragma unroll
    for (int c = 0; c < 4; c++) { el[c] = __expf(sl[c] - ml); ec[c] = __expf(scv[c] - mc); }
    float suml = el[0] + el[1] + el[2] + el[3];
    float sumc = ec[0] + ec[1] + ec[2] + ec[3];
#pragma unroll
    for (int o = 32; o; o >>= 1) { suml += __shfl_xor(suml, o); sumc += __shfl_xor(sumc, o); }
    float rl = __builtin_amdgcn_rcpf(suml), rc = __builtin_amdgcn_rcpf(sumc);
    float4 p;
    p.x = el[0] * rl + ec[0] * rc; p.y = el[1] * rl + ec[1] * rc;
    p.z = el[2] * rl + ec[2] * rc; p.w = el[3] * rl + ec[3] * rc;
    *(float4*)&psw[w][l * 4] = p;
    float acc = 0.f;
#pragma unroll
    for (int jq = 0; jq < 32; jq++) {
      int j4 = hf * 128 + jq * 4;
      float4 pp = *(const float4*)&psw[w][j4];
      float4 vv = *(const float4*)&vst[d][j4];
      acc = fmaf(pp.x, vv.x, acc); acc = fmaf(pp.y, vv.y, acc);
      acc = fmaf(pp.z, vv.z, acc); acc = fmaf(pp.w, vv.w, acc);
    }
    acc += __shfl_xor(acc, 32);
    if (l < 32) out[((size_t)b * N_ + i) * D_ + h * DK_ + d] = acc;
  }
}

// ---- fused edge stream (RT=2; 16-step loop with MANUAL register
//      double-buffer prefetch — forces next-step weight loads to issue
//      before current compute; unroll alone couldn't widen the window).
__global__ __launch_bounds__(256) void e_fused_kernel(
    const u16* __restrict__ e_nb, const u16* __restrict__ scoresT,
    const int* __restrict__ adj1, const u16* __restrict__ wwp,
    const float* __restrict__ edge_fea,
    const u16* __restrict__ woep, const float* __restrict__ lw,
    const float* __restrict__ lb, const u16* __restrict__ w1p,
    const float* __restrict__ b1e, const u16* __restrict__ w2p,
    const float* __restrict__ b2e, float* __restrict__ e_out) {
  __shared__ float e1s[4][32][36];   // fp32 e1 rows (residual + LN input)
  __shared__ float stats[4][2][32];  // mu, inv
  int tid = threadIdx.x;
  int w = tid >> 6, l = tid & 63;
  size_t row0 = (size_t)blockIdx.x * 128 + (size_t)w * 32;
  int kb = (l >> 4) * 8;

  bf16x8 wf0 = *(const bf16x8*)(woep + l * 8);
  bf16x8 wf1 = *(const bf16x8*)(woep + 512 + l * 8);
  bf16x8 wwf0 = *(const bf16x8*)(wwp + l * 8);
  bf16x8 wwf1 = *(const bf16x8*)(wwp + 512 + l * 8);
  f32x4 zero = (f32x4){0.f, 0.f, 0.f, 0.f};
  f32x4 eo[2][2];
#pragma unroll
  for (int rt = 0; rt < 2; rt++) {
    size_t gr = row0 + rt * 16 + (l & 15);
    int a1 = adj1[gr];
    bf16x8 enf = *(const bf16x8*)(e_nb + gr * 32 + kb);
    bf16x8 sf = (bf16x8){0, 0, 0, 0, 0, 0, 0, 0};
    int kg = l >> 4;
    if (kg == 0) {
      const u16* sp = scoresT + ((size_t)(gr >> 8) * 8) * 256 + (gr & 255);
#pragma unroll
      for (int hh = 0; hh < 8; hh++)
        sf[hh] = a1 ? (short)sp[hh * 256] : (short)0;
    } else if (kg == 1) {
      sf[0] = a1 ? (short)0x3F80 : (short)0;  // bf16 1.0
    }
    f32x4 acc0 = __builtin_amdgcn_mfma_f32_16x16x32_bf16(sf, wwf0, zero, 0, 0, 0);
    f32x4 acc1 = __builtin_amdgcn_mfma_f32_16x16x32_bf16(sf, wwf1, zero, 0, 0, 0);
    eo[rt][0] = __builtin_amdgcn_mfma_f32_16x16x32_bf16(enf, wf0, acc0, 0, 0, 0);
    eo[rt][1] = __builtin_amdgcn_mfma_f32_16x16x32_bf16(enf, wf1, acc1, 0, 0, 0);
  }
#pragma unroll
  for (int rt = 0; rt < 2; rt++)
#pragma unroll
    for (int ct = 0; ct < 2; ct++) {
      int col = ct * 16 + (l & 15);
#pragma unroll
      for (int rr = 0; rr < 4; rr++) {
        int row = rt * 16 + (l >> 4) * 4 + rr;
        float ed = edge_fea[(row0 + row) * E_ + col];
        e1s[w][row][col] = ed + eo[rt][ct][rr];
      }
    }

  {
    int r = l >> 1, ch = (l & 1) * 16;
    float4 v0 = *(const float4*)&e1s[w][r][ch + 0];
    float4 v1 = *(const float4*)&e1s[w][r][ch + 4];
    float4 v2 = *(const float4*)&e1s[w][r][ch + 8];
    float4 v3 = *(const float4*)&e1s[w][r][ch + 12];
    float s = v0.x + v0.y + v0.z + v0.w + v1.x + v1.y + v1.z + v1.w +
              v2.x + v2.y + v2.z + v2.w + v3.x + v3.y + v3.z + v3.w;
    s += __shfl_xor(s, 1);
    float mu = s * (1.f / E_);
    float tmp[16] = {v0.x, v0.y, v0.z, v0.w, v1.x, v1.y, v1.z, v1.w,
                     v2.x, v2.y, v2.z, v2.w, v3.x, v3.y, v3.z, v3.w};
    float q = 0.f;
#pragma unroll
    for (int i = 0; i < 16; i++) { float dd = tmp[i] - mu; q += dd * dd; }
    q += __shfl_xor(q, 1);
    float inv = rsqrtf(q * (1.f / E_) + 1e-5f);
    stats[w][0][r] = mu;
    stats[w][1][r] = inv;
  }

  bf16x8 at[2];
  {
    float4 lw0 = *(const float4*)(lw + kb), lw1 = *(const float4*)(lw + kb + 4);
    float4 lb0 = *(const float4*)(lb + kb), lb1 = *(const float4*)(lb + kb + 4);
    float lwv[8] = {lw0.x, lw0.y, lw0.z, lw0.w, lw1.x, lw1.y, lw1.z, lw1.w};
    float lbv[8] = {lb0.x, lb0.y, lb0.z, lb0.w, lb1.x, lb1.y, lb1.z, lb1.w};
#pragma unroll
    for (int rt = 0; rt < 2; rt++) {
      int ar = rt * 16 + (l & 15);
      float mu = stats[w][0][ar], inv = stats[w][1][ar];
      float4 e0 = *(const float4*)&e1s[w][ar][kb];
      float4 e1v = *(const float4*)&e1s[w][ar][kb + 4];
      float ev[8] = {e0.x, e0.y, e0.z, e0.w, e1v.x, e1v.y, e1v.z, e1v.w};
#pragma unroll
      for (int j = 0; j < 8; j++)
        at[rt][j] = (short)f2bf(lwv[j] * (ev[j] - mu) * inv + lbv[j]);
    }
  }

  f32x4 oacc[2][2];
#pragma unroll
  for (int ct = 0; ct < 2; ct++) {
    float bb = b2e[ct * 16 + (l & 15)];
#pragma unroll
    for (int rt = 0; rt < 2; rt++)
      oacc[rt][ct] = (f32x4){bb, bb, bb, bb};
  }

  // ---- main loop with manual prefetch double-buffer
  int lsh = l << 3, brow = (l >> 4) << 2;
  bf16x8 w1c0 = *(const bf16x8*)(w1p + lsh);
  bf16x8 w1c1 = *(const bf16x8*)(w1p + 512 + lsh);
  f16x8 w2c0 = *(const f16x8*)(w2p + lsh);
  f16x8 w2c1 = *(const f16x8*)(w2p + 512 + lsh);
  float4 bc0 = *(const float4*)(b1e + brow);
  float4 bc1 = *(const float4*)(b1e + 16 + brow);
#pragma unroll 4
  for (int st = 0; st < 16; st++) {
    int stn = st < 15 ? st + 1 : 15;
    // prefetch next step's weights (issues before current compute)
    bf16x8 w1n0 = *(const bf16x8*)(w1p + (((size_t)stn * 2 + 0) << 9) + lsh);
    bf16x8 w1n1 = *(const bf16x8*)(w1p + (((size_t)stn * 2 + 1) << 9) + lsh);
    f16x8 w2n0 = *(const f16x8*)(w2p + (((size_t)stn * 2 + 0) << 9) + lsh);
    f16x8 w2n1 = *(const f16x8*)(w2p + (((size_t)stn * 2 + 1) << 9) + lsh);
    float4 bn0 = *(const float4*)(b1e + stn * 32 + brow);
    float4 bn1 = *(const float4*)(b1e + stn * 32 + 16 + brow);
    // compute current step
    f32x4 hi0 = (f32x4){bc0.x, bc0.y, bc0.z, bc0.w};
    f32x4 hi1 = (f32x4){bc1.x, bc1.y, bc1.z, bc1.w};
    f32x4 ht00 = __builtin_amdgcn_mfma_f32_16x16x32_bf16(w1c0, at[0], hi0, 0, 0, 0);
    f32x4 ht01 = __builtin_amdgcn_mfma_f32_16x16x32_bf16(w1c0, at[1], hi0, 0, 0, 0);
    f32x4 ht10 = __builtin_amdgcn_mfma_f32_16x16x32_bf16(w1c1, at[0], hi1, 0, 0, 0);
    f32x4 ht11 = __builtin_amdgcn_mfma_f32_16x16x32_bf16(w1c1, at[1], hi1, 0, 0, 0);
    {
      union { f16x8 v; f16x2 h2[4]; } a8;
      a8.h2[0] = gelu_pk(cvt_pk_f16(ht00[0], ht00[1]));
      a8.h2[1] = gelu_pk(cvt_pk_f16(ht00[2], ht00[3]));
      a8.h2[2] = gelu_pk(cvt_pk_f16(ht10[0], ht10[1]));
      a8.h2[3] = gelu_pk(cvt_pk_f16(ht10[2], ht10[3]));
      oacc[0][0] = __builtin_amdgcn_mfma_f32_16x16x32_f16(a8.v, w2c0, oacc[0][0], 0, 0, 0);
      oacc[0][1] = __builtin_amdgcn_mfma_f32_16x16x32_f16(a8.v, w2c1, oacc[0][1], 0, 0, 0);
    }
    {
      union { f16x8 v; f16x2 h2[4]; } a8;
      a8.h2[0] = gelu_pk(cvt_pk_f16(ht01[0], ht01[1]));
      a8.h2[1] = gelu_pk(cvt_pk_f16(ht01[2], ht01[3]));
      a8.h2[2] = gelu_pk(cvt_pk_f16(ht11[0], ht11[1]));
      a8.h2[3] = gelu_pk(cvt_pk_f16(ht11[2], ht11[3]));
      oacc[1][0] = __builtin_amdgcn_mfma_f32_16x16x32_f16(a8.v, w2c0, oacc[1][0], 0, 0, 0);
      oacc[1][1] = __builtin_amdgcn_mfma_f32_16x16x32_f16(a8.v, w2c1, oacc[1][1], 0, 0, 0);
    }
    // rotate
    w1c0 = w1n0; w1c1 = w1n1; w2c0 = w2n0; w2c1 = w2n1; bc0 = bn0; bc1 = bn1;
  }

  // ---- epilogue: e_out = e1 + O
#pragma unroll
  for (int rt = 0; rt < 2; rt++)
#pragma unroll
    for (int ct = 0; ct < 2; ct++) {
      int col = ct * 16 + (l & 15);
#pragma unroll
      for (int r = 0; r < 4; r++) {
        int rl = rt * 16 + (l >> 4) * 4 + r;
        e_out[(row0 + rl) * E_ + col] = e1s[w][rl][col] + oacc[rt][ct][r];
      }
    }
}

// ---------------------------------------------------------------- launcher
extern "C" void kernel_launch(void* const* d_in, const int* in_sizes, int n_in,
                              void* d_out, int out_size, void* d_ws, size_t ws_size,
                              hipStream_t stream) {
  (void)in_sizes; (void)n_in; (void)out_size; (void)ws_size;
  const float* x        = (const float*)d_in[0];
  const int*   adj      = (const int*)d_in[1];
  const int*   adj1     = (const int*)d_in[2];
  const int*   use_adj  = (const int*)d_in[3];
  const float* edge_fea = (const float*)d_in[4];
  const float* attnb    = (const float*)d_in[5];
  const float* gn1_w = (const float*)d_in[6];
  const float* gn1_b = (const float*)d_in[7];
  const float* gn1_ms = (const float*)d_in[8];
  const float* gn2_w = (const float*)d_in[9];
  const float* gn2_b = (const float*)d_in[10];
  const float* gn2_ms = (const float*)d_in[11];
  const float* ln1_w = (const float*)d_in[12];
  const float* ln1_b = (const float*)d_in[13];
  const float* ln2_w = (const float*)d_in[14];
  const float* ln2_b = (const float*)d_in[15];
  const float* Wq = (const float*)d_in[16];
  const float* bq = (const float*)d_in[17];
  const float* Wk = (const float*)d_in[18];
  const float* bk = (const float*)d_in[19];
  const float* Wv = (const float*)d_in[20];
  const float* bv = (const float*)d_in[21];
  const float* Wap = (const float*)d_in[22];
  const float* bap = (const float*)d_in[23];
  const float* Wep = (const float*)d_in[24];
  const float* bep = (const float*)d_in[25];
  const float* Wo = (const float*)d_in[26];
  const float* bo = (const float*)d_in[27];
  const float* Woe = (const float*)d_in[28];
  const float* W1 = (const float*)d_in[29];
  const float* b1 = (const float*)d_in[30];
  const float* W2 = (const float*)d_in[31];
  const float* b2 = (const float*)d_in[32];
  const float* W1e = (const float*)d_in[33];
  const float* b1e = (const float*)d_in[34];
  const float* W2e = (const float*)d_in[35];
  const float* b2e = (const float*)d_in[36];

  // workspace layout (float offsets) — unchanged from R20 (audited):
  float* ws = (float*)d_ws;
  float* y      = ws;
  float* q      = ws + 262144;
  float* k      = ws + 524288;
  float* v      = ws + 786432;
  float* outs   = ws + 1048576;
  float* x_t    = ws + 1310720;
  float* h1     = ws + 1572864;
  u16*   eb16   = (u16*)(ws + 4194304);
  u16*   e_nb   = (u16*)(ws + 6291456);
  u16*   scoresT= (u16*)(ws + 10485760);
  u16*   wbase  = (u16*)(ws + 11534336);
  u16*   w1p    = wbase;               // 16384 u16
  u16*   w2p    = wbase + 16384;       // 16384 u16 (f16 bits)
  u16*   woep   = wbase + 32768;       // 1024 u16
  u16*   wwp    = wbase + 33792;       // 1024 u16
  float2* gpart = (float2*)(ws + 11551744);  // 8192 float2
  u16*   wxp    = (u16*)(ws + 11568128);     // 524288 u16
  float* x_out  = (float*)d_out;
  float* e_out  = (float*)d_out + 262144;

  dim3 gN(B_, 4, 8);
  front_kernel<<<1472, 256, 0, stream>>>(Wq, Wk, Wv, Wo, W1, W2,
                                         W1e, W2e, Woe, Wap, bap,
                                         wxp, w1p, w2p, woep, wwp,
                                         x, gpart,
                                         edge_fea, ln1_w, ln1_b, Wep, bep, adj1,
                                         e_nb, eb16);
  gnorm_apply_kernel<<<gN, 256, 0, stream>>>(x, gn1_w, gn1_b, gn1_ms, gpart, y);
  qkv_mfma_kernel<<<dim3(4, 32, 3), 256, 0, stream>>>(y, wxp, bq, bk, bv, q, k, v);
  scores_attn_kernel<<<dim3(32, 8, 4), 256, 0, stream>>>(q, k, v, adj, use_adj,
                                                         attnb, eb16, scoresT, outs);
  mgemm_kernel<0><<<dim3(4, 32), 256, 0, stream>>>(outs, wxp + 196608, bo, x, x_t, 256, 256, 1.f);
  gnorm_part_kernel<<<gN, 256, 0, stream>>>(x_t, gpart);
  gnorm_apply_kernel<<<gN, 256, 0, stream>>>(x_t, gn2_w, gn2_b, gn2_ms, gpart, y);
  mgemm_kernel<1><<<dim3(8, 32), 256, 0, stream>>>(y, wxp + 262144, b1, nullptr, h1, 256, 512, 1.f);
  mgemm_kernel<0><<<dim3(4, 32), 256, 0, stream>>>(h1, wxp + 393216, b2, x_t, x_out, 512, 256, 1.f);
  e_fused_kernel<<<2048, 256, 0, stream>>>(e_nb, scoresT, adj1, wwp, edge_fea,
                                           woep, ln2_w, ln2_b, w1p, b1e, w2p, b2e, e_out);
}

// Round 22
// 112.030 us; speedup vs baseline: 1.0424x; 1.0424x over previous
//
#include <hip/hip_runtime.h>
#include <math.h>

// Problem dims
constexpr int B_ = 4, N_ = 256, D_ = 256, H_ = 8, E_ = 32, FF_ = 512, DK_ = 32;
constexpr float SCALE_ = 0.17677669529663687f;  // DK^-0.5
constexpr float NEG_ = -9.0e15f;

typedef unsigned short u16;
typedef unsigned int u32;
typedef __attribute__((ext_vector_type(8))) short bf16x8;
typedef __attribute__((ext_vector_type(4))) float f32x4;
typedef __attribute__((ext_vector_type(8))) _Float16 f16x8;
typedef __attribute__((ext_vector_type(2))) _Float16 f16x2;
typedef __attribute__((ext_vector_type(2))) __fp16 fp16x2_raw;

__device__ __forceinline__ float gelu_fast(float x) {
  float u = x * x;
  float q = x * fmaf(-0.071354816272f, u, -1.5957691216057308f);
  float e = __expf(q);
  return x * __builtin_amdgcn_rcpf(1.f + e);
}

__device__ __forceinline__ f16x2 cvt_pk_f16(float a, float b) {
  union { fp16x2_raw i; f16x2 o; } u;
  u.i = __builtin_amdgcn_cvt_pkrtz(a, b);
  return u.o;
}

// Packed-f16 gelu pair (e-FFN hot loop). |h| <= 0.85 hard bound.
__device__ __forceinline__ f16x2 gelu_pk(f16x2 x) {
  const f16x2 C5 = {(_Float16)0.0199471f, (_Float16)0.0199471f};
  const f16x2 C3 = {(_Float16)-0.1329807f, (_Float16)-0.1329807f};
  const f16x2 C1 = {(_Float16)0.7978846f, (_Float16)0.7978846f};
  const f16x2 HALF = {(_Float16)0.5f, (_Float16)0.5f};
  const f16x2 ONE = {(_Float16)1.f, (_Float16)1.f};
  f16x2 w = x * x;
  f16x2 p = w * C5 + C3;
  p = w * p + C1;
  f16x2 t = x * p + ONE;
  f16x2 hx = x * HALF;
  return hx * t;
}

__device__ __forceinline__ u16 f2bf(float x) {
  union { float f; u32 u; } v; v.f = x;
  u32 r = v.u + 0x7fffu + ((v.u >> 16) & 1u);
  return (u16)(r >> 16);
}

__device__ __forceinline__ u32 pk2bf(float a, float b) {
  union { float f; u32 u; } x, y; x.f = a; y.f = b;
  u32 ra = (x.u + 0x7fffu + ((x.u >> 16) & 1u)) >> 16;
  u32 rb = (y.u + 0x7fffu + ((y.u >> 16) & 1u)) & 0xffff0000u;
  return ra | rb;
}

__device__ __forceinline__ float bf2f(u16 h) {
  union { u32 u; float f; } v; v.u = ((u32)h) << 16; return v.f;
}

// ============ merged FRONT kernel: pack (0..319) | gnorm_part(x) (320..447)
// ============ | ln_e_fused (448..1471). All three mutually independent.
__global__ __launch_bounds__(256) void front_kernel(
    const float* __restrict__ Wq, const float* __restrict__ Wk,
    const float* __restrict__ Wv, const float* __restrict__ Wo,
    const float* __restrict__ W1, const float* __restrict__ W2,
    const float* __restrict__ W1e, const float* __restrict__ W2e,
    const float* __restrict__ Woe, const float* __restrict__ Wap,
    const float* __restrict__ bap,
    u16* __restrict__ wxp, u16* __restrict__ w1p, u16* __restrict__ w2p,
    u16* __restrict__ woep, u16* __restrict__ wwp,
    const float* __restrict__ x, float2* __restrict__ part,
    const float* __restrict__ e_in, const float* __restrict__ lnw,
    const float* __restrict__ lnb, const float* __restrict__ Wep,
    const float* __restrict__ bep, const int* __restrict__ adj1,
    u16* __restrict__ e_nb, u16* __restrict__ eb16) {
  int bx = blockIdx.x;
  int tid = threadIdx.x;
  if (bx < 256) {
    int idx = bx * 256 + tid;
    const float* W;
    int rel, Nn, kcs, cmask;
    if (idx < 32768) {
      int m = idx >> 13;
      W = (m == 0) ? Wq : (m == 1) ? Wk : (m == 2) ? Wv : Wo;
      rel = idx & 8191; Nn = 256; kcs = 4; cmask = 15;
    } else if (idx < 49152) {
      W = W1; rel = idx - 32768; Nn = 512; kcs = 5; cmask = 31;
    } else {
      W = W2; rel = idx - 49152; Nn = 256; kcs = 4; cmask = 15;
    }
    int fr = rel >> 6, lane = rel & 63;
    int kc = fr >> kcs, ctt = fr & cmask;
    int krow = kc * 32 + ((lane >> 4) << 3);
    int col = ctt * 16 + (lane & 15);
    u16 out[8];
#pragma unroll
    for (int j = 0; j < 8; j++)
      out[j] = f2bf(W[(size_t)(krow + j) * Nn + col]);
    uint4* dst = (uint4*)(wxp + ((size_t)idx << 3));
    *dst = make_uint4(((u32)out[0]) | ((u32)out[1] << 16),
                      ((u32)out[2]) | ((u32)out[3] << 16),
                      ((u32)out[4]) | ((u32)out[5] << 16),
                      ((u32)out[6]) | ((u32)out[7] << 16));
  } else if (bx < 320) {
    int idx = (bx - 256) * 256 + tid;  // 0..16383
    {
      int t = idx >> 9, rem = idx & 511, lane = rem >> 3, j = rem & 7;
      int k = ((lane >> 4) << 3) + j, col = (t << 4) + (lane & 15);
      w1p[idx] = f2bf(W1e[k * FF_ + col]);
    }
    {
      int f = idx >> 9, rem = idx & 511, lane = rem >> 3, j = rem & 7;
      int nc = f >> 2, kp = (f >> 1) & 1, ct = f & 1;
      int unit = nc * 64 + kp * 32 + 16 * (j >> 2) + 4 * (lane >> 4) + (j & 3);
      int col = ct * 16 + (lane & 15);
      union { _Float16 h; u16 u; } cv;
      cv.h = (_Float16)W2e[unit * E_ + col];
      w2p[idx] = cv.u;
    }
    if (idx < 1024) {
      int ct = idx >> 9, rem = idx & 511, lane = rem >> 3, j = rem & 7;
      int k = ((lane >> 4) << 3) + j, col = ct * 16 + (lane & 15);
      woep[idx] = f2bf(Woe[k * E_ + col]);
      float v = 0.f;
      if (k < 8) {
        for (int e = 0; e < 32; e++) v += Wap[k * E_ + e] * Woe[e * E_ + col];
      } else if (k == 8) {
        for (int e = 0; e < 32; e++) v += bap[e] * Woe[e * E_ + col];
      }
      wwp[idx] = f2bf(v);
    }
  } else if (bx < 448) {
    int i = bx - 320;
    int b = i & 3, by = (i >> 2) & 3, nz = i >> 4;
    int d = tid & 63, gn = tid >> 6;
    __shared__ float2 red[4][64];
    const float* xp = x + ((size_t)b * N_ * D_) + (size_t)(nz * 32 + gn * 8) * D_ + by * 64 + d;
    float s = 0.f, s2 = 0.f;
#pragma unroll
    for (int i2 = 0; i2 < 8; i2++) { float v = xp[(size_t)i2 * D_]; s += v; s2 += v * v; }
    red[gn][d] = make_float2(s, s2);
    __syncthreads();
    if (tid < 64) {
      float2 a = red[0][d], b2 = red[1][d], c = red[2][d], e = red[3][d];
      part[((b * 4 + by) * 8 + nz) * 64 + d] =
          make_float2(a.x + b2.x + c.x + e.x, a.y + b2.y + c.y + e.y);
    }
  } else {
    size_t t = (size_t)(bx - 448) * 256 + tid;
    int b = (int)(t >> 16), n2 = (int)((t >> 8) & 255), n1 = (int)(t & 255);
    size_t rowid = ((size_t)(b * N_ + n1)) * N_ + n2;
    const float4* ip = (const float4*)(e_in + rowid * E_);
    float4 v[8];
    float s = 0.f;
#pragma unroll
    for (int i = 0; i < 8; i++) { v[i] = ip[i]; s += v[i].x + v[i].y + v[i].z + v[i].w; }
    float mu = s * (1.f / E_);
    float q = 0.f;
#pragma unroll
    for (int i = 0; i < 8; i++) {
      float a = v[i].x - mu, b2 = v[i].y - mu, c = v[i].z - mu, dd = v[i].w - mu;
      q += a * a + b2 * b2 + c * c + dd * dd;
    }
    float inv = rsqrtf(q * (1.f / E_) + 1e-5f);
    float ov[32];
#pragma unroll
    for (int i = 0; i < 8; i++) {
      float4 wv = ((const float4*)lnw)[i];
      float4 bv = ((const float4*)lnb)[i];
      ov[4 * i + 0] = wv.x * (v[i].x - mu) * inv + bv.x;
      ov[4 * i + 1] = wv.y * (v[i].y - mu) * inv + bv.y;
      ov[4 * i + 2] = wv.z * (v[i].z - mu) * inv + bv.z;
      ov[4 * i + 3] = wv.w * (v[i].w - mu) * inv + bv.w;
    }
    u32 pk[16];
#pragma unroll
    for (int i = 0; i < 16; i++) pk[i] = pk2bf(ov[2 * i], ov[2 * i + 1]);
    uint4* op = (uint4*)(e_nb + rowid * E_);
    op[0] = make_uint4(pk[0], pk[1], pk[2], pk[3]);
    op[1] = make_uint4(pk[4], pk[5], pk[6], pk[7]);
    op[2] = make_uint4(pk[8], pk[9], pk[10], pk[11]);
    op[3] = make_uint4(pk[12], pk[13], pk[14], pk[15]);
    float acc[8];
#pragma unroll
    for (int h = 0; h < 8; h++) acc[h] = bep[h];
#pragma unroll
    for (int e = 0; e < 32; e++) {
      float re = ov[e];
#pragma unroll
      for (int h = 0; h < 8; h++) acc[h] = fmaf(re, Wep[e * 8 + h], acc[h]);
    }
    float a1f = (float)adj1[t];
#pragma unroll
    for (int h = 0; h < 8; h++)
      eb16[(((size_t)b * H_ + h) * N_ + n2) * N_ + n1] = f2bf(acc[h] * a1f);
  }
}

// ------------------------------------------- gnorm stage kernels
__global__ __launch_bounds__(256) void gnorm_part_kernel(
    const float* __restrict__ x, float2* __restrict__ part) {
  int b = blockIdx.x, by = blockIdx.y, nz = blockIdx.z;
  int tid = threadIdx.x, d = tid & 63, gn = tid >> 6;
  __shared__ float2 red[4][64];
  const float* xp = x + ((size_t)b * N_ * D_) + (size_t)(nz * 32 + gn * 8) * D_ + by * 64 + d;
  float s = 0.f, s2 = 0.f;
#pragma unroll
  for (int i = 0; i < 8; i++) { float v = xp[(size_t)i * D_]; s += v; s2 += v * v; }
  red[gn][d] = make_float2(s, s2);
  __syncthreads();
  if (tid < 64) {
    float2 a = red[0][d], b2 = red[1][d], c = red[2][d], e = red[3][d];
    part[((b * 4 + by) * 8 + nz) * 64 + d] =
        make_float2(a.x + b2.x + c.x + e.x, a.y + b2.y + c.y + e.y);
  }
}

__global__ __launch_bounds__(256) void gnorm_apply_kernel(
    const float* __restrict__ x, const float* __restrict__ w,
    const float* __restrict__ bw, const float* __restrict__ ms,
    const float2* __restrict__ part, float* __restrict__ out) {
  int b = blockIdx.x, by = blockIdx.y, nz = blockIdx.z;
  int tid = threadIdx.x, d = tid & 63, gn = tid >> 6;
  int d0 = by * 64;
  float s = 0.f, s2 = 0.f;
#pragma unroll
  for (int i = 0; i < 8; i++) {
    float2 p = part[((b * 4 + by) * 8 + i) * 64 + d];
    s += p.x; s2 += p.y;
  }
  float mean = s * (1.f / N_);
  float m2 = ms[d0 + d] * mean;
  float var = fmaxf(s2 * (1.f / N_) - 2.f * m2 * mean + m2 * m2, 0.f);
  float inv = 1.f / (sqrtf(var) + 1e-6f);
  float W = w[d0 + d], Bb = bw[d0 + d];
  const float* xp = x + ((size_t)b * N_ * D_) + (size_t)(nz * 32 + gn * 8) * D_ + d0 + d;
  float* op = out + ((size_t)b * N_ * D_) + (size_t)(nz * 32 + gn * 8) * D_ + d0 + d;
#pragma unroll
  for (int i = 0; i < 8; i++)
    op[(size_t)i * D_] = W * (xp[(size_t)i * D_] - m2) * inv + Bb;
}

// --------------- bf16 MFMA GEMM: 32x64 tile (for Nn=512)
template <int GELU>
__global__ __launch_bounds__(256) void mgemm_kernel(
    const float* __restrict__ A, const u16* __restrict__ Wp,
    const float* __restrict__ bias, const float* __restrict__ res,
    float* __restrict__ C, int K, int Nn, float scale) {
  int tid = threadIdx.x;
  int w = tid >> 6, l = tid & 63;
  int rt = w & 1, cts = (w >> 1) << 1;
  int row0 = blockIdx.y * 32, col0 = blockIdx.x * 64;
  int nf = Nn >> 4;
  f32x4 acc[2];
#pragma unroll
  for (int c2 = 0; c2 < 2; c2++) {
    float bb = bias[col0 + (cts + c2) * 16 + (l & 15)];
    acc[c2] = (f32x4){bb, bb, bb, bb};
  }
  int arow = row0 + rt * 16 + (l & 15);
  const float* ap = A + (size_t)arow * K + ((l >> 4) << 3);
  int nkc = K >> 5;
  for (int kc = 0; kc < nkc; kc++) {
    float4 a0 = *(const float4*)(ap + kc * 32);
    float4 a1 = *(const float4*)(ap + kc * 32 + 4);
    union { bf16x8 v; u32 u[4]; } af;
    af.u[0] = pk2bf(a0.x, a0.y); af.u[1] = pk2bf(a0.z, a0.w);
    af.u[2] = pk2bf(a1.x, a1.y); af.u[3] = pk2bf(a1.z, a1.w);
#pragma unroll
    for (int c2 = 0; c2 < 2; c2++) {
      bf16x8 wf = *(const bf16x8*)(Wp + (((size_t)kc * nf + (col0 >> 4) + cts + c2) << 9) + (l << 3));
      acc[c2] = __builtin_amdgcn_mfma_f32_16x16x32_bf16(af.v, wf, acc[c2], 0, 0, 0);
    }
  }
#pragma unroll
  for (int c2 = 0; c2 < 2; c2++) {
    int col = col0 + (cts + c2) * 16 + (l & 15);
#pragma unroll
    for (int rr = 0; rr < 4; rr++) {
      int row = row0 + rt * 16 + (l >> 4) * 4 + rr;
      float v = acc[c2][rr] * scale;
      if (GELU) v = gelu_fast(v);
      if (res) v += res[(size_t)row * Nn + col];
      C[(size_t)row * Nn + col] = v;
    }
  }
}

// --------------- bf16 MFMA GEMM: 32x32 tile (for Nn=256 -> 256 blocks, full machine)
// 4 waves = 2 row-tiles x 2 col-tiles, 1 MFMA per kc per wave.
template <int GELU>
__global__ __launch_bounds__(256) void mgemm32_kernel(
    const float* __restrict__ A, const u16* __restrict__ Wp,
    const float* __restrict__ bias, const float* __restrict__ res,
    float* __restrict__ C, int K, int Nn, float scale) {
  int tid = threadIdx.x;
  int w = tid >> 6, l = tid & 63;
  int rt = w & 1, ct = w >> 1;
  int row0 = blockIdx.y * 32, col0 = blockIdx.x * 32;
  int nf = Nn >> 4;
  float bb = bias[col0 + ct * 16 + (l & 15)];
  f32x4 acc = (f32x4){bb, bb, bb, bb};
  int arow = row0 + rt * 16 + (l & 15);
  const float* ap = A + (size_t)arow * K + ((l >> 4) << 3);
  int nkc = K >> 5;
  for (int kc = 0; kc < nkc; kc++) {
    float4 a0 = *(const float4*)(ap + kc * 32);
    float4 a1 = *(const float4*)(ap + kc * 32 + 4);
    union { bf16x8 v; u32 u[4]; } af;
    af.u[0] = pk2bf(a0.x, a0.y); af.u[1] = pk2bf(a0.z, a0.w);
    af.u[2] = pk2bf(a1.x, a1.y); af.u[3] = pk2bf(a1.z, a1.w);
    bf16x8 wf = *(const bf16x8*)(Wp + (((size_t)kc * nf + (col0 >> 4) + ct) << 9) + (l << 3));
    acc = __builtin_amdgcn_mfma_f32_16x16x32_bf16(af.v, wf, acc, 0, 0, 0);
  }
  int col = col0 + ct * 16 + (l & 15);
#pragma unroll
  for (int rr = 0; rr < 4; rr++) {
    int row = row0 + rt * 16 + (l >> 4) * 4 + rr;
    float v = acc[rr] * scale;
    if (GELU) v = gelu_fast(v);
    if (res) v += res[(size_t)row * Nn + col];
    C[(size_t)row * Nn + col] = v;
  }
}

// --------------- fused QKV via MFMA (z picks target), K=N=256
__global__ __launch_bounds__(256) void qkv_mfma_kernel(
    const float* __restrict__ A, const u16* __restrict__ wxp,
    const float* __restrict__ bq, const float* __restrict__ bk,
    const float* __restrict__ bv,
    float* __restrict__ q, float* __restrict__ k, float* __restrict__ v) {
  int z = blockIdx.z;
  const u16* Wp = wxp + (size_t)z * 65536;
  const float* bias = (z == 0) ? bq : (z == 1) ? bk : bv;
  float* C = (z == 0) ? q : (z == 1) ? k : v;
  float scale = (z == 0) ? SCALE_ : 1.f;
  int tid = threadIdx.x;
  int w = tid >> 6, l = tid & 63;
  int rt = w & 1, cts = (w >> 1) << 1;
  int row0 = blockIdx.y * 32, col0 = blockIdx.x * 64;
  f32x4 acc[2];
#pragma unroll
  for (int c2 = 0; c2 < 2; c2++) {
    float bb = bias[col0 + (cts + c2) * 16 + (l & 15)];
    acc[c2] = (f32x4){bb, bb, bb, bb};
  }
  int arow = row0 + rt * 16 + (l & 15);
  const float* ap = A + (size_t)arow * D_ + ((l >> 4) << 3);
#pragma unroll
  for (int kc = 0; kc < 8; kc++) {
    float4 a0 = *(const float4*)(ap + kc * 32);
    float4 a1 = *(const float4*)(ap + kc * 32 + 4);
    union { bf16x8 v; u32 u[4]; } af;
    af.u[0] = pk2bf(a0.x, a0.y); af.u[1] = pk2bf(a0.z, a0.w);
    af.u[2] = pk2bf(a1.x, a1.y); af.u[3] = pk2bf(a1.z, a1.w);
#pragma unroll
    for (int c2 = 0; c2 < 2; c2++) {
      bf16x8 wf = *(const bf16x8*)(Wp + (((size_t)kc * 16 + (col0 >> 4) + cts + c2) << 9) + (l << 3));
      acc[c2] = __builtin_amdgcn_mfma_f32_16x16x32_bf16(af.v, wf, acc[c2], 0, 0, 0);
    }
  }
#pragma unroll
  for (int c2 = 0; c2 < 2; c2++) {
    int col = col0 + (cts + c2) * 16 + (l & 15);
#pragma unroll
    for (int rr = 0; rr < 4; rr++) {
      int row = row0 + rt * 16 + (l >> 4) * 4 + rr;
      C[(size_t)row * D_ + col] = acc[c2][rr] * scale;
    }
  }
}

// ===== FUSED scores + dual-softmax + PV (R20-proven): 16 q-rows/block,
// grid (16,8,4)=512. K row direct to regs; V staged transposed.
__global__ __launch_bounds__(256) void scores_attn_kernel(
    const float* __restrict__ q, const float* __restrict__ k,
    const float* __restrict__ v, const int* __restrict__ adj,
    const int* __restrict__ use_adj, const float* __restrict__ ab,
    const u16* __restrict__ eb16,
    u16* __restrict__ scoresT, float* __restrict__ out) {
  int it2 = blockIdx.x, h = blockIdx.y, b = blockIdx.z;  // it2: 0..15, 16 rows
  int tid = threadIdx.x;
  __shared__ float qt[16][33];
  __shared__ u16 sc[16][260];     // bf16 scores
  __shared__ float vst[32][260];  // V transposed [d][j]
  __shared__ float psw[4][256];   // wave-private p rows

  float kreg[32];
  {
    const float4* kp = (const float4*)(k + ((size_t)b * N_ + tid) * D_ + h * DK_);
#pragma unroll
    for (int i = 0; i < 8; i++) {
      float4 kv = kp[i];
      kreg[4 * i] = kv.x; kreg[4 * i + 1] = kv.y;
      kreg[4 * i + 2] = kv.z; kreg[4 * i + 3] = kv.w;
    }
  }
  for (int i2 = 0; i2 < 2; i2++) {
    int f = tid + (i2 << 8);
    int rr = f >> 5, d = f & 31;
    qt[rr][d] = q[((size_t)b * N_ + it2 * 16 + rr) * D_ + h * DK_ + d];
  }
  for (int i2 = 0; i2 < 32; i2++) {
    int f = tid + (i2 << 8);
    int j = f >> 5, d = f & 31;
    vst[d][j] = v[((size_t)b * N_ + j) * D_ + h * DK_ + d];
  }
  __syncthreads();

  int ua = use_adj[0];
  u32 sbuf[8];
  float sprev = 0.f;
#pragma unroll
  for (int r = 0; r < 16; r++) {
    float s = 0.f;
#pragma unroll
    for (int d = 0; d < 32; d++) s = fmaf(qt[r][d], kreg[d], s);
    int i = it2 * 16 + r;
    if (ua) {
      int a = adj[((size_t)b * N_ + i) * N_ + tid];
      s = (a > 0 ? s : NEG_) * (float)a;
    }
    sc[r][tid] = f2bf(s);
    if (r & 1) sbuf[r >> 1] = pk2bf(sprev, s); else sprev = s;
  }
  uint4* stp = (uint4*)(scoresT + ((((size_t)(b * N_ + tid)) * 8 + h) << 8) + (it2 << 4));
  stp[0] = make_uint4(sbuf[0], sbuf[1], sbuf[2], sbuf[3]);
  stp[1] = make_uint4(sbuf[4], sbuf[5], sbuf[6], sbuf[7]);
  __syncthreads();

  int w = tid >> 6, l = tid & 63;
  int d = l & 31, hf = l >> 5;
  for (int rr = 0; rr < 4; rr++) {
    int lr = w * 4 + rr;
    int i = it2 * 16 + lr;
    size_t base = (((size_t)b * H_ + h) * N_ + i) * N_ + l * 4;
    uint2 sB = *(const uint2*)&sc[lr][l * 4];
    float s4x = bf2f((u16)(sB.x & 0xffff)), s4y = bf2f((u16)(sB.x >> 16));
    float s4z = bf2f((u16)(sB.y & 0xffff)), s4w = bf2f((u16)(sB.y >> 16));
    uint2 eB = *(const uint2*)(eb16 + base);
    float e4x = bf2f((u16)(eB.x & 0xffff)), e4y = bf2f((u16)(eB.x >> 16));
    float e4z = bf2f((u16)(eB.y & 0xffff)), e4w = bf2f((u16)(eB.y >> 16));
    float4 a4 = *(const float4*)(ab + base);
    float sl[4] = {s4x * a4.x, s4y * a4.y, s4z * a4.z, s4w * a4.w};
    float scv[4] = {s4x * e4x, s4y * e4y, s4z * e4z, s4w * e4w};
    float ml = fmaxf(fmaxf(sl[0], sl[1]), fmaxf(sl[2], sl[3]));
    float mc = fmaxf(fmaxf(scv[0], scv[1]), fmaxf(scv[2], scv[3]));
#pragma unroll
    for (int o = 32; o; o >>= 1) { ml = fmaxf(ml, __shfl_xor(ml, o)); mc = fmaxf(mc, __shfl_xor(mc, o)); }
    float el[4], ec[4];
#pragma unroll
    for (int c = 0; c < 4; c++) { el[c] = __expf(sl[c] - ml); ec[c] = __expf(scv[c] - mc); }
    float suml = el[0] + el[1] + el[2] + el[3];
    float sumc = ec[0] + ec[1] + ec[2] + ec[3];
#pragma unroll
    for (int o = 32; o; o >>= 1) { suml += __shfl_xor(suml, o); sumc += __shfl_xor(sumc, o); }
    float rl = __builtin_amdgcn_rcpf(suml), rc = __builtin_amdgcn_rcpf(sumc);
    float4 p;
    p.x = el[0] * rl + ec[0] * rc; p.y = el[1] * rl + ec[1] * rc;
    p.z = el[2] * rl + ec[2] * rc; p.w = el[3] * rl + ec[3] * rc;
    *(float4*)&psw[w][l * 4] = p;
    float acc = 0.f;
#pragma unroll
    for (int jq = 0; jq < 32; jq++) {
      int j4 = hf * 128 + jq * 4;
      float4 pp = *(const float4*)&psw[w][j4];
      float4 vv = *(const float4*)&vst[d][j4];
      acc = fmaf(pp.x, vv.x, acc); acc = fmaf(pp.y, vv.y, acc);
      acc = fmaf(pp.z, vv.z, acc); acc = fmaf(pp.w, vv.w, acc);
    }
    acc += __shfl_xor(acc, 32);
    if (l < 32) out[((size_t)b * N_ + i) * D_ + h * DK_ + d] = acc;
  }
}

// ---- fused edge stream (R20-proven: RT=2; 16-step main loop, unroll 4)
__global__ __launch_bounds__(256) void e_fused_kernel(
    const u16* __restrict__ e_nb, const u16* __restrict__ scoresT,
    const int* __restrict__ adj1, const u16* __restrict__ wwp,
    const float* __restrict__ edge_fea,
    const u16* __restrict__ woep, const float* __restrict__ lw,
    const float* __restrict__ lb, const u16* __restrict__ w1p,
    const float* __restrict__ b1e, const u16* __restrict__ w2p,
    const float* __restrict__ b2e, float* __restrict__ e_out) {
  __shared__ float e1s[4][32][36];   // fp32 e1 rows (residual + LN input)
  __shared__ float stats[4][2][32];  // mu, inv
  int tid = threadIdx.x;
  int w = tid >> 6, l = tid & 63;
  size_t row0 = (size_t)blockIdx.x * 128 + (size_t)w * 32;
  int kb = (l >> 4) * 8;

  bf16x8 wf0 = *(const bf16x8*)(woep + l * 8);
  bf16x8 wf1 = *(const bf16x8*)(woep + 512 + l * 8);
  bf16x8 wwf0 = *(const bf16x8*)(wwp + l * 8);
  bf16x8 wwf1 = *(const bf16x8*)(wwp + 512 + l * 8);
  f32x4 zero = (f32x4){0.f, 0.f, 0.f, 0.f};
  f32x4 eo[2][2];
#pragma unroll
  for (int rt = 0; rt < 2; rt++) {
    size_t gr = row0 + rt * 16 + (l & 15);
    int a1 = adj1[gr];
    bf16x8 enf = *(const bf16x8*)(e_nb + gr * 32 + kb);
    bf16x8 sf = (bf16x8){0, 0, 0, 0, 0, 0, 0, 0};
    int kg = l >> 4;
    if (kg == 0) {
      const u16* sp = scoresT + ((size_t)(gr >> 8) * 8) * 256 + (gr & 255);
#pragma unroll
      for (int hh = 0; hh < 8; hh++)
        sf[hh] = a1 ? (short)sp[hh * 256] : (short)0;
    } else if (kg == 1) {
      sf[0] = a1 ? (short)0x3F80 : (short)0;  // bf16 1.0
    }
    f32x4 acc0 = __builtin_amdgcn_mfma_f32_16x16x32_bf16(sf, wwf0, zero, 0, 0, 0);
    f32x4 acc1 = __builtin_amdgcn_mfma_f32_16x16x32_bf16(sf, wwf1, zero, 0, 0, 0);
    eo[rt][0] = __builtin_amdgcn_mfma_f32_16x16x32_bf16(enf, wf0, acc0, 0, 0, 0);
    eo[rt][1] = __builtin_amdgcn_mfma_f32_16x16x32_bf16(enf, wf1, acc1, 0, 0, 0);
  }
#pragma unroll
  for (int rt = 0; rt < 2; rt++)
#pragma unroll
    for (int ct = 0; ct < 2; ct++) {
      int col = ct * 16 + (l & 15);
#pragma unroll
      for (int rr = 0; rr < 4; rr++) {
        int row = rt * 16 + (l >> 4) * 4 + rr;
        float ed = edge_fea[(row0 + row) * E_ + col];
        e1s[w][row][col] = ed + eo[rt][ct][rr];
      }
    }

  {
    int r = l >> 1, ch = (l & 1) * 16;
    float4 v0 = *(const float4*)&e1s[w][r][ch + 0];
    float4 v1 = *(const float4*)&e1s[w][r][ch + 4];
    float4 v2 = *(const float4*)&e1s[w][r][ch + 8];
    float4 v3 = *(const float4*)&e1s[w][r][ch + 12];
    float s = v0.x + v0.y + v0.z + v0.w + v1.x + v1.y + v1.z + v1.w +
              v2.x + v2.y + v2.z + v2.w + v3.x + v3.y + v3.z + v3.w;
    s += __shfl_xor(s, 1);
    float mu = s * (1.f / E_);
    float tmp[16] = {v0.x, v0.y, v0.z, v0.w, v1.x, v1.y, v1.z, v1.w,
                     v2.x, v2.y, v2.z, v2.w, v3.x, v3.y, v3.z, v3.w};
    float q = 0.f;
#pragma unroll
    for (int i = 0; i < 16; i++) { float dd = tmp[i] - mu; q += dd * dd; }
    q += __shfl_xor(q, 1);
    float inv = rsqrtf(q * (1.f / E_) + 1e-5f);
    stats[w][0][r] = mu;
    stats[w][1][r] = inv;
  }

  bf16x8 at[2];
  {
    float4 lw0 = *(const float4*)(lw + kb), lw1 = *(const float4*)(lw + kb + 4);
    float4 lb0 = *(const float4*)(lb + kb), lb1 = *(const float4*)(lb + kb + 4);
    float lwv[8] = {lw0.x, lw0.y, lw0.z, lw0.w, lw1.x, lw1.y, lw1.z, lw1.w};
    float lbv[8] = {lb0.x, lb0.y, lb0.z, lb0.w, lb1.x, lb1.y, lb1.z, lb1.w};
#pragma unroll
    for (int rt = 0; rt < 2; rt++) {
      int ar = rt * 16 + (l & 15);
      float mu = stats[w][0][ar], inv = stats[w][1][ar];
      float4 e0 = *(const float4*)&e1s[w][ar][kb];
      float4 e1v = *(const float4*)&e1s[w][ar][kb + 4];
      float ev[8] = {e0.x, e0.y, e0.z, e0.w, e1v.x, e1v.y, e1v.z, e1v.w};
#pragma unroll
      for (int j = 0; j < 8; j++)
        at[rt][j] = (short)f2bf(lwv[j] * (ev[j] - mu) * inv + lbv[j]);
    }
  }

  f32x4 oacc[2][2];
#pragma unroll
  for (int ct = 0; ct < 2; ct++) {
    float bb = b2e[ct * 16 + (l & 15)];
#pragma unroll
    for (int rt = 0; rt < 2; rt++)
      oacc[rt][ct] = (f32x4){bb, bb, bb, bb};
  }

#pragma unroll 4
  for (int st = 0; st < 16; st++) {
    bf16x8 w1f0 = *(const bf16x8*)(w1p + (((size_t)st * 2 + 0) << 9) + (l << 3));
    bf16x8 w1f1 = *(const bf16x8*)(w1p + (((size_t)st * 2 + 1) << 9) + (l << 3));
    f16x8 w2f0 = *(const f16x8*)(w2p + (((size_t)st * 2 + 0) << 9) + (l << 3));
    f16x8 w2f1 = *(const f16x8*)(w2p + (((size_t)st * 2 + 1) << 9) + (l << 3));
    float4 b40 = *(const float4*)(b1e + st * 32 + ((l >> 4) << 2));
    float4 b41 = *(const float4*)(b1e + st * 32 + 16 + ((l >> 4) << 2));
    f32x4 hi0 = (f32x4){b40.x, b40.y, b40.z, b40.w};
    f32x4 hi1 = (f32x4){b41.x, b41.y, b41.z, b41.w};
    f32x4 ht00 = __builtin_amdgcn_mfma_f32_16x16x32_bf16(w1f0, at[0], hi0, 0, 0, 0);
    f32x4 ht01 = __builtin_amdgcn_mfma_f32_16x16x32_bf16(w1f0, at[1], hi0, 0, 0, 0);
    f32x4 ht10 = __builtin_amdgcn_mfma_f32_16x16x32_bf16(w1f1, at[0], hi1, 0, 0, 0);
    f32x4 ht11 = __builtin_amdgcn_mfma_f32_16x16x32_bf16(w1f1, at[1], hi1, 0, 0, 0);
    {
      union { f16x8 v; f16x2 h2[4]; } a8;
      a8.h2[0] = gelu_pk(cvt_pk_f16(ht00[0], ht00[1]));
      a8.h2[1] = gelu_pk(cvt_pk_f16(ht00[2], ht00[3]));
      a8.h2[2] = gelu_pk(cvt_pk_f16(ht10[0], ht10[1]));
      a8.h2[3] = gelu_pk(cvt_pk_f16(ht10[2], ht10[3]));
      oacc[0][0] = __builtin_amdgcn_mfma_f32_16x16x32_f16(a8.v, w2f0, oacc[0][0], 0, 0, 0);
      oacc[0][1] = __builtin_amdgcn_mfma_f32_16x16x32_f16(a8.v, w2f1, oacc[0][1], 0, 0, 0);
    }
    {
      union { f16x8 v; f16x2 h2[4]; } a8;
      a8.h2[0] = gelu_pk(cvt_pk_f16(ht01[0], ht01[1]));
      a8.h2[1] = gelu_pk(cvt_pk_f16(ht01[2], ht01[3]));
      a8.h2[2] = gelu_pk(cvt_pk_f16(ht11[0], ht11[1]));
      a8.h2[3] = gelu_pk(cvt_pk_f16(ht11[2], ht11[3]));
      oacc[1][0] = __builtin_amdgcn_mfma_f32_16x16x32_f16(a8.v, w2f0, oacc[1][0], 0, 0, 0);
      oacc[1][1] = __builtin_amdgcn_mfma_f32_16x16x32_f16(a8.v, w2f1, oacc[1][1], 0, 0, 0);
    }
  }

#pragma unroll
  for (int rt = 0; rt < 2; rt++)
#pragma unroll
    for (int ct = 0; ct < 2; ct++) {
      int col = ct * 16 + (l & 15);
#pragma unroll
      for (int r = 0; r < 4; r++) {
        int rl = rt * 16 + (l >> 4) * 4 + r;
        e_out[(row0 + rl) * E_ + col] = e1s[w][rl][col] + oacc[rt][ct][r];
      }
    }
}

// ---------------------------------------------------------------- launcher
extern "C" void kernel_launch(void* const* d_in, const int* in_sizes, int n_in,
                              void* d_out, int out_size, void* d_ws, size_t ws_size,
                              hipStream_t stream) {
  (void)in_sizes; (void)n_in; (void)out_size; (void)ws_size;
  const float* x        = (const float*)d_in[0];
  const int*   adj      = (const int*)d_in[1];
  const int*   adj1     = (const int*)d_in[2];
  const int*   use_adj  = (const int*)d_in[3];
  const float* edge_fea = (const float*)d_in[4];
  const float* attnb    = (const float*)d_in[5];
  const float* gn1_w = (const float*)d_in[6];
  const float* gn1_b = (const float*)d_in[7];
  const float* gn1_ms = (const float*)d_in[8];
  const float* gn2_w = (const float*)d_in[9];
  const float* gn2_b = (const float*)d_in[10];
  const float* gn2_ms = (const float*)d_in[11];
  const float* ln1_w = (const float*)d_in[12];
  const float* ln1_b = (const float*)d_in[13];
  const float* ln2_w = (const float*)d_in[14];
  const float* ln2_b = (const float*)d_in[15];
  const float* Wq = (const float*)d_in[16];
  const float* bq = (const float*)d_in[17];
  const float* Wk = (const float*)d_in[18];
  const float* bk = (const float*)d_in[19];
  const float* Wv = (const float*)d_in[20];
  const float* bv = (const float*)d_in[21];
  const float* Wap = (const float*)d_in[22];
  const float* bap = (const float*)d_in[23];
  const float* Wep = (const float*)d_in[24];
  const float* bep = (const float*)d_in[25];
  const float* Wo = (const float*)d_in[26];
  const float* bo = (const float*)d_in[27];
  const float* Woe = (const float*)d_in[28];
  const float* W1 = (const float*)d_in[29];
  const float* b1 = (const float*)d_in[30];
  const float* W2 = (const float*)d_in[31];
  const float* b2 = (const float*)d_in[32];
  const float* W1e = (const float*)d_in[33];
  const float* b1e = (const float*)d_in[34];
  const float* W2e = (const float*)d_in[35];
  const float* b2e = (const float*)d_in[36];

  // workspace layout (float offsets) — unchanged from R20 (audited):
  float* ws = (float*)d_ws;
  float* y      = ws;
  float* q      = ws + 262144;
  float* k      = ws + 524288;
  float* v      = ws + 786432;
  float* outs   = ws + 1048576;
  float* x_t    = ws + 1310720;
  float* h1     = ws + 1572864;
  u16*   eb16   = (u16*)(ws + 4194304);
  u16*   e_nb   = (u16*)(ws + 6291456);
  u16*   scoresT= (u16*)(ws + 10485760);
  u16*   wbase  = (u16*)(ws + 11534336);
  u16*   w1p    = wbase;               // 16384 u16
  u16*   w2p    = wbase + 16384;       // 16384 u16 (f16 bits)
  u16*   woep   = wbase + 32768;       // 1024 u16
  u16*   wwp    = wbase + 33792;       // 1024 u16
  float2* gpart = (float2*)(ws + 11551744);  // 8192 float2
  u16*   wxp    = (u16*)(ws + 11568128);     // 524288 u16
  float* x_out  = (float*)d_out;
  float* e_out  = (float*)d_out + 262144;

  dim3 gN(B_, 4, 8);
  front_kernel<<<1472, 256, 0, stream>>>(Wq, Wk, Wv, Wo, W1, W2,
                                         W1e, W2e, Woe, Wap, bap,
                                         wxp, w1p, w2p, woep, wwp,
                                         x, gpart,
                                         edge_fea, ln1_w, ln1_b, Wep, bep, adj1,
                                         e_nb, eb16);
  gnorm_apply_kernel<<<gN, 256, 0, stream>>>(x, gn1_w, gn1_b, gn1_ms, gpart, y);
  qkv_mfma_kernel<<<dim3(4, 32, 3), 256, 0, stream>>>(y, wxp, bq, bk, bv, q, k, v);
  scores_attn_kernel<<<dim3(16, 8, 4), 256, 0, stream>>>(q, k, v, adj, use_adj,
                                                         attnb, eb16, scoresT, outs);
  mgemm32_kernel<0><<<dim3(8, 32), 256, 0, stream>>>(outs, wxp + 196608, bo, x, x_t, 256, 256, 1.f);
  gnorm_part_kernel<<<gN, 256, 0, stream>>>(x_t, gpart);
  gnorm_apply_kernel<<<gN, 256, 0, stream>>>(x_t, gn2_w, gn2_b, gn2_ms, gpart, y);
  mgemm_kernel<1><<<dim3(8, 32), 256, 0, stream>>>(y, wxp + 262144, b1, nullptr, h1, 256, 512, 1.f);
  mgemm32_kernel<0><<<dim3(8, 32), 256, 0, stream>>>(h1, wxp + 393216, b2, x_t, x_out, 512, 256, 1.f);
  e_fused_kernel<<<2048, 256, 0, stream>>>(e_nb, scoresT, adj1, wwp, edge_fea,
                                           woep, ln2_w, ln2_b, w1p, b1e, w2p, b2e, e_out);
}